// Round 6
// baseline (4080.894 us; speedup 1.0000x reference)
//
#include <hip/hip_runtime.h>

#define SEQ 2048
#define D 128

// ---------------------------------------------------------------------------
// Kernel 1: per-step J-independent quantities (fully parallel), UNNORMALIZED:
//   alpha_i = k_s . q_i      (i <= s)
//   kqq[s]  = sum alpha_i^2          = l * (k^T Sqq_l k)
//   sl[s]   = sum alpha_i (v_s.v_i)  = l * (k^T Sqv_l v)
//   vv[s]   = v_s . v_s
//   U[s][c] = sum_i q_i[c] alpha_i   = l * (Sqq_l k)[c]
//   invl[s] = 1.0 / l   (fp64, for cost rescale)
// Round 6: pass 2 gets 4 independent accumulators (was a single dependent
// fma chain ~1024 deep for the largest blocks).
// ---------------------------------------------------------------------------
__global__ __launch_bounds__(256) void precompute_kernel(
    const float* __restrict__ q, const float* __restrict__ k, const float* __restrict__ v,
    float* __restrict__ U, float* __restrict__ sl, float* __restrict__ kqq,
    float* __restrict__ vv, double* __restrict__ invl)
{
    const int s = blockIdx.x;
    const int tid = threadIdx.x;

    __shared__ float ks[D];
    __shared__ float vs[D];
    __shared__ float alpha[SEQ];
    __shared__ float red[8];
    __shared__ float upart[256];

    if (tid < D) ks[tid] = k[s * D + tid];
    else if (tid < 2 * D) vs[tid - D] = v[s * D + (tid - D)];
    __syncthreads();

    float p_a2 = 0.f, p_ab = 0.f;
    for (int i = tid; i <= s; i += 256) {
        const float4* qr = (const float4*)(q + (size_t)i * D);
        const float4* vr = (const float4*)(v + (size_t)i * D);
        float a = 0.f, b = 0.f;
#pragma unroll
        for (int j = 0; j < D / 4; ++j) {
            float4 q4 = qr[j];
            float4 v4 = vr[j];
            a += q4.x * ks[4 * j + 0] + q4.y * ks[4 * j + 1] + q4.z * ks[4 * j + 2] + q4.w * ks[4 * j + 3];
            b += v4.x * vs[4 * j + 0] + v4.y * vs[4 * j + 1] + v4.z * vs[4 * j + 2] + v4.w * vs[4 * j + 3];
        }
        alpha[i] = a;
        p_a2 += a * a;
        p_ab += a * b;
        if (i == s) vv[s] = b;  // v_s . v_s
    }
#pragma unroll
    for (int off = 1; off < 64; off <<= 1) {
        p_a2 += __shfl_xor(p_a2, off);
        p_ab += __shfl_xor(p_ab, off);
    }
    const int wid = tid >> 6;
    if ((tid & 63) == 0) { red[wid] = p_a2; red[4 + wid] = p_ab; }
    __syncthreads();  // also makes alpha[] visible to everyone
    if (tid == 0) {
        kqq[s] = red[0] + red[1] + red[2] + red[3];
        sl[s]  = red[4] + red[5] + red[6] + red[7];
        invl[s] = 1.0 / (double)(s + 1);
    }

    // pass 2: U[s][c] = sum_i q[i][c] * alpha[i], i parity-split over h,
    // 4 independent accumulators to break the dependent fma chain
    const int c = tid & (D - 1);
    const int h = tid >> 7;  // 0 or 1
    float a0 = 0.f, a1 = 0.f, a2 = 0.f, a3 = 0.f;
    int i = h;
    for (; i + 6 <= s; i += 8) {
        a0 = fmaf(q[(size_t)(i    ) * D + c], alpha[i    ], a0);
        a1 = fmaf(q[(size_t)(i + 2) * D + c], alpha[i + 2], a1);
        a2 = fmaf(q[(size_t)(i + 4) * D + c], alpha[i + 4], a2);
        a3 = fmaf(q[(size_t)(i + 6) * D + c], alpha[i + 6], a3);
    }
    for (; i <= s; i += 2) a0 = fmaf(q[(size_t)i * D + c], alpha[i], a0);
    upart[tid] = (a0 + a1) + (a2 + a3);
    __syncthreads();
    if (tid < D) U[(size_t)s * D + tid] = upart[tid] + upart[tid + D];
}

// ---------------------------------------------------------------------------
// Kernel 2: sequential scan, one 512-thread workgroup (8 waves, 2/SIMD).
// ROUND-6: ONE barrier per step, no wave0-exclusive region.
//   wave w = column group (c0 = w*16, wave-uniform); lane l owns rows l and
//   64+l; thread holds J[rowA][c0:c0+16] + J[rowB][c0:c0+16] = 32 floats in
//   named float4 regs (round-5-verified spill-free scheme, 2 rows).
// Per step:
//   dot (64 FMA) -> linear scalars Jqv,AJl reduced IN-WAVE pre-barrier
//   (they're linear in cg-partials); pq row-partials + 2 floats to LDS
//   (parity double-buffer, conflict-free [cg][129] layout) -> BARRIER ->
//   every wave redundantly: assemble row sums (8 b32 reads), Jq2 via
//   6-shfl, Jqv/AJl via broadcast float4 reads, fp64 chain (lazy divides),
//   J update. Decisions identical on all lanes -> no broadcast needed.
// Next-step q/u/k (wave-uniform chunks), v elements, and scalars are
// register-prefetched pre-barrier; k stays live through the update.
// ---------------------------------------------------------------------------
__global__ __launch_bounds__(512, 2) void scan_kernel(
    const float* __restrict__ q, const float* __restrict__ k, const float* __restrict__ v,
    const float* __restrict__ U, const float* __restrict__ sl_arr,
    const float* __restrict__ kqq_arr, const float* __restrict__ vv_arr,
    const double* __restrict__ invl_arr,
    float* __restrict__ out)  // [0,2048) costs | [2048,4096) updated | [4096,...) J
{
    const int tid = threadIdx.x;
    const int l   = tid & 63;
    const int w   = __builtin_amdgcn_readfirstlane(tid >> 6);  // 0..7, uniform
    const int c0  = w * 16;
    const int rA  = l;
    const int rB  = 64 + l;

    float4 ja0 = make_float4(0.f,0.f,0.f,0.f), ja1 = ja0, ja2 = ja0, ja3 = ja0;
    float4 jb0 = ja0, jb1 = ja0, jb2 = ja0, jb3 = ja0;

    __shared__ float partQ[2][8][129];  // [parity][cg][row(+pad)] pq partials
    __shared__ float wredF[2][16];      // [parity][cg*2 + {t1,t3}]

    // ---- prologue: step-0 operands ----
    const float4* qp = (const float4*)(q + c0);
    float4 qc0 = qp[0], qc1 = qp[1], qc2 = qp[2], qc3 = qp[3];
    const float4* up = (const float4*)(U + c0);
    float4 uc0 = up[0], uc1 = up[1], uc2 = up[2], uc3 = up[3];
    const float4* kp = (const float4*)(k + c0);
    float4 kc0 = kp[0], kc1 = kp[1], kc2 = kp[2], kc3 = kp[3];
    float vA = v[rA], vB = v[rB];
    float  slc = sl_arr[0], kqc = kqq_arr[0], vvc = vv_arr[0];
    double invc = invl_arr[0];

    double SJ = 0.0, AJJ = 0.0, trSvv = 0.0;   // identical on all threads

#define DOT16(RES, B0, B1, B2, B3, X0, X1, X2, X3)                             \
    {                                                                          \
        float u0 = B0.x * X0.x, u1 = B2.x * X2.x;                              \
        u0 = fmaf(B0.y, X0.y, u0); u1 = fmaf(B2.y, X2.y, u1);                  \
        u0 = fmaf(B0.z, X0.z, u0); u1 = fmaf(B2.z, X2.z, u1);                  \
        u0 = fmaf(B0.w, X0.w, u0); u1 = fmaf(B2.w, X2.w, u1);                  \
        u0 = fmaf(B1.x, X1.x, u0); u1 = fmaf(B3.x, X3.x, u1);                  \
        u0 = fmaf(B1.y, X1.y, u0); u1 = fmaf(B3.y, X3.y, u1);                  \
        u0 = fmaf(B1.z, X1.z, u0); u1 = fmaf(B3.z, X3.z, u1);                  \
        u0 = fmaf(B1.w, X1.w, u0); u1 = fmaf(B3.w, X3.w, u1);                  \
        RES = u0 + u1;                                                         \
    }

    for (int s = 0; s < SEQ; ++s) {
        const int par = s & 1;

        // ---- dots over my 16 columns, 2 rows ----
        float pqA, puA, pqB, puB;
        DOT16(pqA, ja0, ja1, ja2, ja3, qc0, qc1, qc2, qc3)
        DOT16(puA, ja0, ja1, ja2, ja3, uc0, uc1, uc2, uc3)
        DOT16(pqB, jb0, jb1, jb2, jb3, qc0, qc1, qc2, qc3)
        DOT16(puB, jb0, jb1, jb2, jb3, uc0, uc1, uc2, uc3)

        // ---- linear scalars: in-wave reduce (per-cg partials of Jqv, AJl) --
        float t1 = vA * pqA + vB * pqB;   // -> sum_r v_r (Jq)_r  (this cg)
        float t3 = vA * puA + vB * puB;   // -> sum_r v_r (Ju)_r  (this cg)
#pragma unroll
        for (int off = 1; off < 64; off <<= 1) {
            t1 += __shfl_xor(t1, off);
            t3 += __shfl_xor(t3, off);
        }

        // ---- LDS: pq row-partials + per-wave linear sums ----
        partQ[par][w][rA] = pqA;
        partQ[par][w][rB] = pqB;
        if (l == 0) { wredF[par][2 * w] = t1; wredF[par][2 * w + 1] = t3; }

        // ---- prefetch next-step operands (latency hidden by barrier+reduce)
        const int sn = (s + 1 < SEQ) ? s + 1 : SEQ - 1;
        const float4* qpn = (const float4*)(q + (size_t)sn * D + c0);
        const float4 qn0 = qpn[0], qn1 = qpn[1], qn2 = qpn[2], qn3 = qpn[3];
        const float4* upn = (const float4*)(U + (size_t)sn * D + c0);
        const float4 un0 = upn[0], un1 = upn[1], un2 = upn[2], un3 = upn[3];
        const float4* kpn = (const float4*)(k + (size_t)sn * D + c0);
        const float4 kn0 = kpn[0], kn1 = kpn[1], kn2 = kpn[2], kn3 = kpn[3];
        const float vAn = v[(size_t)sn * D + rA], vBn = v[(size_t)sn * D + rB];
        const float  sln = sl_arr[sn], kqn = kqq_arr[sn], vvn = vv_arr[sn];
        const double invn = invl_arr[sn];

        __syncthreads();  // the ONE barrier

        // ---- Jq2: assemble full row sums, square, in-wave reduce ----
        float sA = 0.f, sB = 0.f;
#pragma unroll
        for (int cg = 0; cg < 8; ++cg) {
            sA += partQ[par][cg][rA];
            sB += partQ[par][cg][rB];
        }
        float sq = sA * sA + sB * sB;
#pragma unroll
        for (int off = 1; off < 64; off <<= 1) sq += __shfl_xor(sq, off);

        // ---- Jqv / AJl: broadcast read of the 8 wave sums ----
        const float4* wr = (const float4*)&wredF[par][0];
        const float4 e0 = wr[0], e1 = wr[1], e2 = wr[2], e3 = wr[3];
        const float Jqvf = ((e0.x + e0.z) + (e1.x + e1.z)) + ((e2.x + e2.z) + (e3.x + e3.z));
        const float AJlf = ((e0.y + e0.w) + (e1.y + e1.w)) + ((e2.y + e2.w) + (e3.y + e3.w));

        // ---- fp64 decision chain (identical on all threads) ----
        trSvv += (double)vvc;
        SJ    += (double)Jqvf;
        AJJ   += (double)sq;
        const double s_l  = (double)slc;
        const double A_ll = (double)vvc * (double)kqc;
        const double AJl  = (double)AJlf;
        const bool first = (s == 0);
        const double AJJ_s  = (first || AJJ == 0.0)  ? 1.0 : AJJ;   // > 0 always
        const double A_ll_s = (first || A_ll == 0.0) ? 1.0 : A_ll;
        const double denom   = AJJ * A_ll - AJl * AJl;
        const double denom_s = (first || denom == 0.0) ? 1.0 : denom;
        const double rden = 1.0 / denom_s;
        const double wf = (A_ll * SJ - AJl * s_l) * rden;
        const double wi = (AJJ * s_l - AJl * SJ) * rden;
        double wf_c, wi_c;
        if (wi <= 0.0)      { wf_c = SJ / AJJ_s;  wi_c = 0.0; }
        else if (wf <= 0.0) { wf_c = 0.0;         wi_c = s_l / A_ll_s; }
        else                { wf_c = wf;          wi_c = wi; }
        const bool do_update = (s_l * AJJ_s - AJl * SJ) > 0.0;  // margin * AJJ_s

        int mode;
        if (first) {
            mode = 2;
            SJ  = s_l;    // tr(vk^T Sqv') = k^T Sqv' v
            AJJ = A_ll;   // (v.v)(k^T Sqq' k)
        } else if (do_update) {
            mode = 1;
            const double nSJ = wf_c * SJ + wi_c * s_l;
            AJJ = wf_c * wf_c * AJJ + 2.0 * wf_c * wi_c * AJl + wi_c * wi_c * A_ll;
            SJ = nSJ;
        } else {
            mode = 0;
        }

        if (tid == 0) {
            out[s] = (float)((0.5 * trSvv - SJ + 0.5 * AJJ) * invc);
            out[SEQ + s] = (mode != 0) ? 1.f : 0.f;
        }

        // ---- J update (wave-uniform branch; pure register ops) ----
        if (mode == 2) {
            ja0.x = vA*kc0.x; ja0.y = vA*kc0.y; ja0.z = vA*kc0.z; ja0.w = vA*kc0.w;
            ja1.x = vA*kc1.x; ja1.y = vA*kc1.y; ja1.z = vA*kc1.z; ja1.w = vA*kc1.w;
            ja2.x = vA*kc2.x; ja2.y = vA*kc2.y; ja2.z = vA*kc2.z; ja2.w = vA*kc2.w;
            ja3.x = vA*kc3.x; ja3.y = vA*kc3.y; ja3.z = vA*kc3.z; ja3.w = vA*kc3.w;
            jb0.x = vB*kc0.x; jb0.y = vB*kc0.y; jb0.z = vB*kc0.z; jb0.w = vB*kc0.w;
            jb1.x = vB*kc1.x; jb1.y = vB*kc1.y; jb1.z = vB*kc1.z; jb1.w = vB*kc1.w;
            jb2.x = vB*kc2.x; jb2.y = vB*kc2.y; jb2.z = vB*kc2.z; jb2.w = vB*kc2.w;
            jb3.x = vB*kc3.x; jb3.y = vB*kc3.y; jb3.z = vB*kc3.z; jb3.w = vB*kc3.w;
        } else if (mode == 1) {
            const float wff = (float)wf_c;
            const float wiA = (float)wi_c * vA;
            const float wiB = (float)wi_c * vB;
            ja0.x = fmaf(ja0.x, wff, wiA*kc0.x); ja0.y = fmaf(ja0.y, wff, wiA*kc0.y);
            ja0.z = fmaf(ja0.z, wff, wiA*kc0.z); ja0.w = fmaf(ja0.w, wff, wiA*kc0.w);
            ja1.x = fmaf(ja1.x, wff, wiA*kc1.x); ja1.y = fmaf(ja1.y, wff, wiA*kc1.y);
            ja1.z = fmaf(ja1.z, wff, wiA*kc1.z); ja1.w = fmaf(ja1.w, wff, wiA*kc1.w);
            ja2.x = fmaf(ja2.x, wff, wiA*kc2.x); ja2.y = fmaf(ja2.y, wff, wiA*kc2.y);
            ja2.z = fmaf(ja2.z, wff, wiA*kc2.z); ja2.w = fmaf(ja2.w, wff, wiA*kc2.w);
            ja3.x = fmaf(ja3.x, wff, wiA*kc3.x); ja3.y = fmaf(ja3.y, wff, wiA*kc3.y);
            ja3.z = fmaf(ja3.z, wff, wiA*kc3.z); ja3.w = fmaf(ja3.w, wff, wiA*kc3.w);
            jb0.x = fmaf(jb0.x, wff, wiB*kc0.x); jb0.y = fmaf(jb0.y, wff, wiB*kc0.y);
            jb0.z = fmaf(jb0.z, wff, wiB*kc0.z); jb0.w = fmaf(jb0.w, wff, wiB*kc0.w);
            jb1.x = fmaf(jb1.x, wff, wiB*kc1.x); jb1.y = fmaf(jb1.y, wff, wiB*kc1.y);
            jb1.z = fmaf(jb1.z, wff, wiB*kc1.z); jb1.w = fmaf(jb1.w, wff, wiB*kc1.w);
            jb2.x = fmaf(jb2.x, wff, wiB*kc2.x); jb2.y = fmaf(jb2.y, wff, wiB*kc2.y);
            jb2.z = fmaf(jb2.z, wff, wiB*kc2.z); jb2.w = fmaf(jb2.w, wff, wiB*kc2.w);
            jb3.x = fmaf(jb3.x, wff, wiB*kc3.x); jb3.y = fmaf(jb3.y, wff, wiB*kc3.y);
            jb3.z = fmaf(jb3.z, wff, wiB*kc3.z); jb3.w = fmaf(jb3.w, wff, wiB*kc3.w);
        }

        // ---- shift prefetched operands ----
        qc0 = qn0; qc1 = qn1; qc2 = qn2; qc3 = qn3;
        uc0 = un0; uc1 = un1; uc2 = un2; uc3 = un3;
        kc0 = kn0; kc1 = kn1; kc2 = kn2; kc3 = kn3;
        vA = vAn; vB = vBn;
        slc = sln; kqc = kqn; vvc = vvn; invc = invn;
    }
#undef DOT16

    // final J (row-major [d_v][d_k]) — rows rA and rB, cols c0..c0+15
    {
        float* ja = out + 2 * SEQ + (size_t)rA * D + c0;
        *(float4*)(ja + 0)  = ja0;
        *(float4*)(ja + 4)  = ja1;
        *(float4*)(ja + 8)  = ja2;
        *(float4*)(ja + 12) = ja3;
        float* jb = out + 2 * SEQ + (size_t)rB * D + c0;
        *(float4*)(jb + 0)  = jb0;
        *(float4*)(jb + 4)  = jb1;
        *(float4*)(jb + 8)  = jb2;
        *(float4*)(jb + 12) = jb3;
    }
}

extern "C" void kernel_launch(void* const* d_in, const int* in_sizes, int n_in,
                              void* d_out, int out_size, void* d_ws, size_t ws_size,
                              hipStream_t stream) {
    (void)in_sizes; (void)n_in; (void)out_size; (void)ws_size;
    const float* q = (const float*)d_in[0];
    const float* k = (const float*)d_in[1];
    const float* v = (const float*)d_in[2];
    float* out = (float*)d_out;

    float* U    = (float*)d_ws;             // SEQ*D floats (1 MB)
    float* sl   = U + (size_t)SEQ * D;      // SEQ
    float* kqq  = sl + SEQ;                 // SEQ
    float* vv   = kqq + SEQ;                // SEQ
    double* invl = (double*)(vv + SEQ);     // SEQ doubles (8B-aligned)

    precompute_kernel<<<SEQ, 256, 0, stream>>>(q, k, v, U, sl, kqq, vv, invl);
    scan_kernel<<<1, 512, 0, stream>>>(q, k, v, U, sl, kqq, vv, invl, out);
}